// Round 8
// baseline (57.734 us; speedup 1.0000x reference)
//
#include <hip/hip_runtime.h>
#include <math.h>

#define H_ 768
#define W_ 768
#define TY 16
#define TX 64
#define NTHREADS 256
#define EPS_ 1e-6f

// sB geometry: column c <-> global col gx0 - 6 + c (OFF=6), so each thread's
// 8-float window (global cols lx4-2..lx4+5) starts at sB col lx4+4, which is
// 16B-aligned. Row width 76 (multiple of 4 words) keeps alignment per row.
#define SBW 76
#define OFF 6

typedef float f4 __attribute__((ext_vector_type(4)));

__device__ __forceinline__ f4 mk4(float x, float y, float z, float w){ f4 r; r.x=x; r.y=y; r.z=z; r.w=w; return r; }
__device__ __forceinline__ f4 sp(float s){ return mk4(s,s,s,s); }
__device__ __forceinline__ f4 max4(f4 a, f4 b){ return mk4(fmaxf(a.x,b.x),fmaxf(a.y,b.y),fmaxf(a.z,b.z),fmaxf(a.w,b.w)); }
__device__ __forceinline__ f4 sqrt4(f4 a){ return mk4(sqrtf(a.x),sqrtf(a.y),sqrtf(a.z),sqrtf(a.w)); }
__device__ __forceinline__ f4 abs4(f4 a){ return mk4(fabsf(a.x),fabsf(a.y),fabsf(a.z),fabsf(a.w)); }
__device__ __forceinline__ float rcp1(float x){
#if __has_builtin(__builtin_amdgcn_rcpf)
    return __builtin_amdgcn_rcpf(x);
#else
    return 1.0f / x;
#endif
}
__device__ __forceinline__ f4 rcp4(f4 a){ return mk4(rcp1(a.x),rcp1(a.y),rcp1(a.z),rcp1(a.w)); }

__device__ __forceinline__ int refl(int c, int n) {
    c = c < 0 ? -c : c;
    return c >= n ? 2 * n - 2 - c : c;
}

// Round-7 structure (best: 45.8us) with ONE isolated change: all channel
// stores are nontemporal (evict-first / L2-bypass hint) since output is
// write-once streaming data that is never re-read by this kernel.
__global__ __launch_bounds__(NTHREADS, 4)
void bayer_feat(const float* __restrict__ in, float* __restrict__ out) {
    const int bz  = blockIdx.z;
    const int gy0 = blockIdx.y * TY;
    const int gx0 = blockIdx.x * TX;
    const int tid = threadIdx.x;
    const float* src = in + (size_t)bz * (H_ * W_);

    __shared__ __align__(16) float sB[TY + 6][SBW];   // bayer tile, halo 3
    __shared__ float sE[7][TY + 2][TX + 3];           // gx, gy, hgh, hgv, chk, stx, sty (halo 1)

    for (int i = tid; i < (TY + 6) * (TX + 6); i += NTHREADS) {
        int r = i / (TX + 6), c = i - r * (TX + 6);
        sB[r][c + 3] = src[refl(gy0 - 3 + r, H_) * W_ + refl(gx0 - 3 + c, W_)];
    }
    __syncthreads();

    for (int i = tid; i < (TY + 2) * (TX + 2); i += NTHREADS) {
        int ey = i / (TX + 2), ex = i - ey * (TX + 2);
        int sy = refl(gy0 - 1 + ey, H_) - gy0 + 3;
        int sx = refl(gx0 - 1 + ex, W_) - gx0 + OFF;
        float a00 = sB[sy-1][sx-1], a01 = sB[sy-1][sx], a02 = sB[sy-1][sx+1];
        float a10 = sB[sy  ][sx-1], a11 = sB[sy  ][sx], a12 = sB[sy  ][sx+1];
        float a20 = sB[sy+1][sx-1], a21 = sB[sy+1][sx], a22 = sB[sy+1][sx+1];
        float l2 = sB[sy][sx-2], r2 = sB[sy][sx+2];
        float u2 = sB[sy-2][sx], d2 = sB[sy+2][sx];
        sE[0][ey][ex] = 0.125f * (-a00 + a02 - 2.f*a10 + 2.f*a12 - a20 + a22);
        sE[1][ey][ex] = 0.125f * (-a00 - 2.f*a01 - a02 + a20 + 2.f*a21 + a22);
        sE[2][ey][ex] = -0.25f*(l2 + r2) + 0.5f*(a10 + a11 + a12);
        sE[3][ey][ex] = -0.25f*(u2 + d2) + 0.5f*(a01 + a11 + a21);
        sE[4][ey][ex] = (a00 - a01 + a02 - a10 + a11 - a12 + a20 - a21 + a22) * (1.f/9.f);
        sE[5][ey][ex] = 0.25f*(l2 + r2) - (a10 + a12) + 1.5f*a11;
        sE[6][ey][ex] = 0.25f*(u2 + d2) - (a01 + a21) + 1.5f*a11;
    }
    __syncthreads();

    // thread -> 1x4 horizontal strip
    const int lq  = tid & 15;
    const int ly  = tid >> 4;
    const int lx4 = lq * 4;
    const int gy  = gy0 + ly;
    const int py  = gy & 1;                  // px per component = (0,1,0,1)
    const int syc = ly + 3;
    const int ey  = ly + 1;
    const int exb = lx4 + 1;
    const size_t HW = (size_t)H_ * W_;
    float* po = out + (size_t)bz * 52 * HW + (size_t)gy * W_ + (gx0 + lx4);

#define ST(c, v) __builtin_nontemporal_store((v), (f4*)(po + (size_t)(c) * HW))
#define AV(r, i) mk4(a[r][i], a[r][(i)+1], a[r][(i)+2], a[r][(i)+3])
#define SL(arr, o) mk4(arr[o], arr[(o)+1], arr[(o)+2], arr[(o)+3])
#define CTR(f) mk4(sE[f][ey][exb], sE[f][ey][exb+1], sE[f][ey][exb+2], sE[f][ey][exb+3])

    const f4 zero4 = sp(0.f);
    const f4 ev01  = mk4(0,1,0,1);
    const f4 ev10  = mk4(1,0,1,0);
    const float inv9 = 1.f / 9.f;

    // register window: rows syc-2..syc+2, global cols lx4-2..lx4+5
    // sB col lx4+4+i -> 16B-aligned -> 2x ds_read_b128 per row
    float a[5][8];
#pragma unroll
    for (int r = 0; r < 5; ++r) {
        f4 lo = *(const f4*)&sB[syc - 2 + r][lx4 + 4];
        f4 hi = *(const f4*)&sB[syc - 2 + r][lx4 + 8];
        a[r][0]=lo.x; a[r][1]=lo.y; a[r][2]=lo.z; a[r][3]=lo.w;
        a[r][4]=hi.x; a[r][5]=hi.y; a[r][6]=hi.z; a[r][7]=hi.w;
    }

    // ================= PHASE A: full-window channels first =================

    // gabor45 / gabor135 / dct
    {
        const float G45[5][5] = {
            {-0.002092f, -0.015195f, -0.063321f, -0.002285f,  0.036511f},
            {-0.015195f, -0.086304f,  0.003803f,  0.119456f, -0.002285f},
            {-0.063321f,  0.003803f,  0.172851f,  0.003803f, -0.063321f},
            {-0.002285f,  0.119456f,  0.003803f, -0.086304f, -0.015195f},
            { 0.036511f, -0.002285f, -0.063321f, -0.015195f, -0.002092f}
        };
        const float ADC[5] = {0.25f, -0.09549150f, -0.30901699f, -0.09549150f, 0.25f};
        f4 s45 = zero4, s135 = zero4, dct = zero4;
#pragma unroll
        for (int r = 0; r < 5; ++r) {
            f4 t = zero4;
#pragma unroll
            for (int i = 0; i < 5; ++i) {
                f4 v = AV(r, i);
                s45  += sp(G45[r][i])     * v;
                s135 += sp(G45[r][4 - i]) * v;
                t    += sp(ADC[i])        * v;
            }
            dct += sp(ADC[r]) * t;
        }
        ST(44, s45); ST(45, s135); ST(46, dct);
    }

    // normalized sparse fills (parity closed-form)
    {
        f4 t0 = zero4, t1 = zero4, t2 = zero4, t3 = zero4;
#pragma unroll
        for (int r = 0; r < 5; ++r) {
            f4 E = AV(r,0) + sp(3.f)*AV(r,2) + AV(r,4);
            f4 O = sp(2.f)*(AV(r,1) + AV(r,3));
            f4 rE = mk4(E.x, O.y, E.z, O.w);
            f4 rO = mk4(O.x, E.y, O.z, E.w);
            if (r == 0 || r == 4)      { t0 += rE;          t2 += rO; }
            else if (r == 2)           { t0 += sp(3.f)*rE;  t2 += sp(3.f)*rO; }
            else                       { t1 += sp(2.f)*rE;  t3 += sp(2.f)*rO; }
        }
        f4 cEE = py ? t1 : t0, cOE = py ? t0 : t1, cEO = py ? t3 : t2, cOO = py ? t2 : t3;
        const f4 inv_r  = py ? mk4(0.04f,0.05f,0.04f,0.05f)     : mk4(0.05f,0.0625f,0.05f,0.0625f);
        const f4 inv_b  = py ? mk4(0.0625f,0.05f,0.0625f,0.05f) : mk4(0.05f,0.04f,0.05f,0.04f);
        const f4 inv_gr = py ? mk4(0.05f,0.04f,0.05f,0.04f)     : mk4(0.0625f,0.05f,0.0625f,0.05f);
        const f4 inv_gb = py ? mk4(0.05f,0.0625f,0.05f,0.0625f) : mk4(0.04f,0.05f,0.04f,0.05f);
        const f4 inv_g  = py ? mk4(1.f/40.f,1.f/41.f,1.f/40.f,1.f/41.f)
                             : mk4(1.f/41.f,1.f/40.f,1.f/41.f,1.f/40.f);
        f4 rfv = cOE*inv_r, bfv = cEO*inv_b, grfv = cOO*inv_gr, gbfv = cEE*inv_gb;
        f4 gfv = (cEE + cOO)*inv_g;
        ST(34, rfv - gfv); ST(35, bfv - gfv); ST(36, grfv - gbfv);
    }

    f4 ctr = AV(2,2);

    // 1x5 / 5x1 line variances
    {
        f4 sh = AV(2,0)+AV(2,1)+ctr+AV(2,3)+AV(2,4);
        f4 qh = AV(2,0)*AV(2,0)+AV(2,1)*AV(2,1)+ctr*ctr+AV(2,3)*AV(2,3)+AV(2,4)*AV(2,4);
        f4 sv_ = AV(0,2)+AV(1,2)+ctr+AV(3,2)+AV(4,2);
        f4 qv_ = AV(0,2)*AV(0,2)+AV(1,2)*AV(1,2)+ctr*ctr+AV(3,2)*AV(3,2)+AV(4,2)*AV(4,2);
        f4 mh = sh * sp(0.2f), mv = sv_ * sp(0.2f);
        f4 lvh = max4(qh*sp(0.2f) - mh*mh, zero4);
        f4 lvv = max4(qv_*sp(0.2f) - mv*mv, zero4);
        ST(30, lvh); ST(31, lvv);
        f4 lvd = lvh - lvv;
        ST(32, lvd);
        ST(33, abs4(lvd) * rcp4(lvh + lvv + sp(EPS_)));
    }

    ST(19, sp(-0.5f)*(AV(2,0) + AV(2,4)) + ctr);
    ST(20, sp(-0.5f)*(AV(0,2) + AV(4,2)) + ctr);

    // MHC (needs +-2 cross); hgh/hgv centers read from sE
    f4 hghv = CTR(2), hgvv = CTR(3);
    {
        f4 mhcf = sp(0.125f)*( -AV(0,2) + sp(2.f)*AV(1,2) - AV(2,0) + sp(2.f)*AV(2,1) + sp(4.f)*ctr
                               + sp(2.f)*AV(2,3) - AV(2,4) + sp(2.f)*AV(3,2) - AV(4,2) );
        f4 mhc = py ? mk4(mhcf.x, ctr.y, mhcf.z, ctr.w) : mk4(ctr.x, mhcf.y, ctr.z, mhcf.w);
        ST(37, mhc);
        ST(38, mhc - sp(0.5f)*(hghv + hgvv));
        f4 dif = ctr - mhc;
        ST(39, dif * (py ? ev10 : zero4));
        ST(40, dif * (py ? zero4 : ev01));
    }
    ST(21, hghv); ST(22, hgvv);
    ST(23, abs4(hghv - hgvv));
    ST(24, ctr - hghv); ST(25, ctr - hgvv);

    // 3x3 stencils
    {
        f4 lap = AV(1,2) + AV(2,1) - sp(4.f)*ctr + AV(2,3) + AV(3,2);
        f4 hxx = AV(2,1) - sp(2.f)*ctr + AV(2,3);
        f4 hyy = AV(1,2) - sp(2.f)*ctr + AV(3,2);
        f4 hxy = sp(0.25f)*(AV(1,1) - AV(1,3) - AV(3,1) + AV(3,3));
        ST(7, lap); ST(8, hxx); ST(9, hyy); ST(10, hxy);
        ST(29, abs4(hxx) - abs4(hyy));
    }
    ST(14, sp(0.125f)*(sp(-2.f)*AV(1,1) - AV(1,2) - AV(2,1) + AV(2,3) + AV(3,2) + sp(2.f)*AV(3,3)));
    ST(15, sp(0.125f)*(AV(1,2) + sp(2.f)*AV(1,3) - AV(2,1) + AV(2,3) - sp(2.f)*AV(3,1) - AV(3,2)));

    {   // morphological gradient + local mean/var (3x3)
        f4 mx = AV(1,1), mn = mx, s3 = zero4, q3 = zero4;
#pragma unroll
        for (int r = 1; r <= 3; ++r)
#pragma unroll
            for (int i = 1; i <= 3; ++i) {
                f4 v = AV(r,i);
                mx = max4(mx, v);
                mn = mk4(fminf(mn.x,v.x),fminf(mn.y,v.y),fminf(mn.z,v.z),fminf(mn.w,v.w));
                s3 += v; q3 += v*v;
            }
        ST(11, mx - mn);
        f4 lmean = s3 * sp(inv9);
        ST(49, lmean);
        ST(50, max4(q3*sp(inv9) - lmean*lmean, zero4));
    }

    // center-field channels
    {
        f4 gxv = CTR(0), gyv = CTR(1);
        ST(12, gxv); ST(13, gyv);
        ST(16, sqrt4(gxv*gxv + gyv*gyv + sp(EPS_)));
        ST(28, abs4(gxv) - abs4(gyv));
    }
    ST(41, CTR(5)); ST(42, CTR(6)); ST(43, CTR(4));

    // ================= PHASE B: 3x3 box filters over ext fields =================
    {
        f4 jxx = zero4, jyy = zero4, jxy = zero4, reh = zero4, rev = zero4, cke = zero4, ste = zero4;
#pragma unroll
        for (int dy = -1; dy <= 1; ++dy) {
            float g_[6], h_[6], hh_[6], hv_[6], ck_[6], sx_[6], sy_[6];
#pragma unroll
            for (int j = 0; j < 6; ++j) {
                g_[j]  = sE[0][ey+dy][exb-1+j];
                h_[j]  = sE[1][ey+dy][exb-1+j];
                hh_[j] = sE[2][ey+dy][exb-1+j];
                hv_[j] = sE[3][ey+dy][exb-1+j];
                ck_[j] = sE[4][ey+dy][exb-1+j];
                sx_[j] = sE[5][ey+dy][exb-1+j];
                sy_[j] = sE[6][ey+dy][exb-1+j];
            }
            f4 bm_ = AV(dy+2, 1), b0_ = AV(dy+2, 2), bp_ = AV(dy+2, 3);
#pragma unroll
            for (int o = 0; o < 3; ++o) {
                f4 q = SL(g_, o), w = SL(h_, o);
                jxx += q*q; jyy += w*w; jxy += q*w;
                f4 bb = (o == 0) ? bm_ : (o == 1 ? b0_ : bp_);
                f4 rh = bb - SL(hh_, o); reh += rh*rh;
                f4 rv = bb - SL(hv_, o); rev += rv*rv;
                f4 cc = SL(ck_, o); cke += cc*cc;
                f4 s1 = SL(sx_, o), s2 = SL(sy_, o);
                ste += s1*s1 + s2*s2;
            }
        }
        jxx = jxx * sp(inv9); jyy = jyy * sp(inv9); jxy = jxy * sp(inv9);
        f4 trc = jxx + jyy;
        f4 dj  = jxx - jyy;
        f4 lam = sqrt4(dj*dj + sp(4.f)*jxy*jxy + sp(EPS_));
        f4 itr = rcp4(trc + sp(EPS_));
        ST(17, lam * itr);
        ST(18, dj * itr);
        ST(51, trc);
        ST(26, reh * sp(inv9)); ST(27, rev * sp(inv9));
        ST(47, cke * sp(inv9)); ST(48, ste * sp(inv9));
    }

    // ================= masks last =================
    ST(0, py ? ev10 : zero4);
    ST(1, py ? ev01 : ev10);
    ST(2, py ? zero4 : ev01);
    ST(3, py ? ev01 : zero4);
    ST(4, py ? zero4 : ev10);
    ST(5, sp((float)py));
    ST(6, ev01);

#undef ST
#undef AV
#undef SL
#undef CTR
}

extern "C" void kernel_launch(void* const* d_in, const int* in_sizes, int n_in,
                              void* d_out, int out_size, void* d_ws, size_t ws_size,
                              hipStream_t stream) {
    (void)n_in; (void)d_ws; (void)ws_size; (void)out_size;
    const float* bayer = (const float*)d_in[0];
    float* out = (float*)d_out;
    const int B = in_sizes[0] / (H_ * W_);
    dim3 grid(W_ / TX, H_ / TY, B);
    bayer_feat<<<grid, NTHREADS, 0, stream>>>(bayer, out);
}

// Round 9
// 45.725 us; speedup vs baseline: 1.2626x; 1.2626x over previous
//
#include <hip/hip_runtime.h>
#include <math.h>

#define H_ 768
#define W_ 768
#define TY 16
#define TX 64
#define NTHREADS 256
#define EPS_ 1e-6f

// sB geometry: column c <-> global col gx0 - 6 + c (OFF=6), so each thread's
// 8-float window (global cols lx4-2..lx4+5) starts at sB col lx4+4, which is
// 16B-aligned. Row width 76 (multiple of 4 words) keeps alignment per row.
#define SBW 76
#define OFF 6

typedef float f4 __attribute__((ext_vector_type(4)));

__device__ __forceinline__ f4 mk4(float x, float y, float z, float w){ f4 r; r.x=x; r.y=y; r.z=z; r.w=w; return r; }
__device__ __forceinline__ f4 sp(float s){ return mk4(s,s,s,s); }
__device__ __forceinline__ f4 max4(f4 a, f4 b){ return mk4(fmaxf(a.x,b.x),fmaxf(a.y,b.y),fmaxf(a.z,b.z),fmaxf(a.w,b.w)); }
__device__ __forceinline__ f4 sqrt4(f4 a){ return mk4(sqrtf(a.x),sqrtf(a.y),sqrtf(a.z),sqrtf(a.w)); }
__device__ __forceinline__ f4 abs4(f4 a){ return mk4(fabsf(a.x),fabsf(a.y),fabsf(a.z),fabsf(a.w)); }
__device__ __forceinline__ float rcp1(float x){
#if __has_builtin(__builtin_amdgcn_rcpf)
    return __builtin_amdgcn_rcpf(x);
#else
    return 1.0f / x;
#endif
}
__device__ __forceinline__ f4 rcp4(f4 a){ return mk4(rcp1(a.x),rcp1(a.y),rcp1(a.z),rcp1(a.w)); }

__device__ __forceinline__ int refl(int c, int n) {
    c = c < 0 ? -c : c;
    return c >= n ? 2 * n - 2 - c : c;
}

// Round-7 winner, verbatim (45.8us). NT stores measured -26% (round 8) and
// reverted: on gfx950 the streaming write path benefits from normal L2
// write allocation; `nt` defeats it.
__global__ __launch_bounds__(NTHREADS, 4)
void bayer_feat(const float* __restrict__ in, float* __restrict__ out) {
    const int bz  = blockIdx.z;
    const int gy0 = blockIdx.y * TY;
    const int gx0 = blockIdx.x * TX;
    const int tid = threadIdx.x;
    const float* src = in + (size_t)bz * (H_ * W_);

    __shared__ __align__(16) float sB[TY + 6][SBW];   // bayer tile, halo 3
    __shared__ float sE[7][TY + 2][TX + 3];           // gx, gy, hgh, hgv, chk, stx, sty (halo 1)

    for (int i = tid; i < (TY + 6) * (TX + 6); i += NTHREADS) {
        int r = i / (TX + 6), c = i - r * (TX + 6);
        sB[r][c + 3] = src[refl(gy0 - 3 + r, H_) * W_ + refl(gx0 - 3 + c, W_)];
    }
    __syncthreads();

    for (int i = tid; i < (TY + 2) * (TX + 2); i += NTHREADS) {
        int ey = i / (TX + 2), ex = i - ey * (TX + 2);
        int sy = refl(gy0 - 1 + ey, H_) - gy0 + 3;
        int sx = refl(gx0 - 1 + ex, W_) - gx0 + OFF;
        float a00 = sB[sy-1][sx-1], a01 = sB[sy-1][sx], a02 = sB[sy-1][sx+1];
        float a10 = sB[sy  ][sx-1], a11 = sB[sy  ][sx], a12 = sB[sy  ][sx+1];
        float a20 = sB[sy+1][sx-1], a21 = sB[sy+1][sx], a22 = sB[sy+1][sx+1];
        float l2 = sB[sy][sx-2], r2 = sB[sy][sx+2];
        float u2 = sB[sy-2][sx], d2 = sB[sy+2][sx];
        sE[0][ey][ex] = 0.125f * (-a00 + a02 - 2.f*a10 + 2.f*a12 - a20 + a22);
        sE[1][ey][ex] = 0.125f * (-a00 - 2.f*a01 - a02 + a20 + 2.f*a21 + a22);
        sE[2][ey][ex] = -0.25f*(l2 + r2) + 0.5f*(a10 + a11 + a12);
        sE[3][ey][ex] = -0.25f*(u2 + d2) + 0.5f*(a01 + a11 + a21);
        sE[4][ey][ex] = (a00 - a01 + a02 - a10 + a11 - a12 + a20 - a21 + a22) * (1.f/9.f);
        sE[5][ey][ex] = 0.25f*(l2 + r2) - (a10 + a12) + 1.5f*a11;
        sE[6][ey][ex] = 0.25f*(u2 + d2) - (a01 + a21) + 1.5f*a11;
    }
    __syncthreads();

    // thread -> 1x4 horizontal strip
    const int lq  = tid & 15;
    const int ly  = tid >> 4;
    const int lx4 = lq * 4;
    const int gy  = gy0 + ly;
    const int py  = gy & 1;                  // px per component = (0,1,0,1)
    const int syc = ly + 3;
    const int ey  = ly + 1;
    const int exb = lx4 + 1;
    const size_t HW = (size_t)H_ * W_;
    float* po = out + (size_t)bz * 52 * HW + (size_t)gy * W_ + (gx0 + lx4);

#define ST(c, v) *(f4*)(po + (size_t)(c) * HW) = (v)
#define AV(r, i) mk4(a[r][i], a[r][(i)+1], a[r][(i)+2], a[r][(i)+3])
#define SL(arr, o) mk4(arr[o], arr[(o)+1], arr[(o)+2], arr[(o)+3])
#define CTR(f) mk4(sE[f][ey][exb], sE[f][ey][exb+1], sE[f][ey][exb+2], sE[f][ey][exb+3])

    const f4 zero4 = sp(0.f);
    const f4 ev01  = mk4(0,1,0,1);
    const f4 ev10  = mk4(1,0,1,0);
    const float inv9 = 1.f / 9.f;

    // register window: rows syc-2..syc+2, global cols lx4-2..lx4+5
    // sB col lx4+4+i -> 16B-aligned -> 2x ds_read_b128 per row
    float a[5][8];
#pragma unroll
    for (int r = 0; r < 5; ++r) {
        f4 lo = *(const f4*)&sB[syc - 2 + r][lx4 + 4];
        f4 hi = *(const f4*)&sB[syc - 2 + r][lx4 + 8];
        a[r][0]=lo.x; a[r][1]=lo.y; a[r][2]=lo.z; a[r][3]=lo.w;
        a[r][4]=hi.x; a[r][5]=hi.y; a[r][6]=hi.z; a[r][7]=hi.w;
    }

    // ================= PHASE A: full-window channels first =================

    // gabor45 / gabor135 / dct
    {
        const float G45[5][5] = {
            {-0.002092f, -0.015195f, -0.063321f, -0.002285f,  0.036511f},
            {-0.015195f, -0.086304f,  0.003803f,  0.119456f, -0.002285f},
            {-0.063321f,  0.003803f,  0.172851f,  0.003803f, -0.063321f},
            {-0.002285f,  0.119456f,  0.003803f, -0.086304f, -0.015195f},
            { 0.036511f, -0.002285f, -0.063321f, -0.015195f, -0.002092f}
        };
        const float ADC[5] = {0.25f, -0.09549150f, -0.30901699f, -0.09549150f, 0.25f};
        f4 s45 = zero4, s135 = zero4, dct = zero4;
#pragma unroll
        for (int r = 0; r < 5; ++r) {
            f4 t = zero4;
#pragma unroll
            for (int i = 0; i < 5; ++i) {
                f4 v = AV(r, i);
                s45  += sp(G45[r][i])     * v;
                s135 += sp(G45[r][4 - i]) * v;
                t    += sp(ADC[i])        * v;
            }
            dct += sp(ADC[r]) * t;
        }
        ST(44, s45); ST(45, s135); ST(46, dct);
    }

    // normalized sparse fills (parity closed-form)
    {
        f4 t0 = zero4, t1 = zero4, t2 = zero4, t3 = zero4;
#pragma unroll
        for (int r = 0; r < 5; ++r) {
            f4 E = AV(r,0) + sp(3.f)*AV(r,2) + AV(r,4);
            f4 O = sp(2.f)*(AV(r,1) + AV(r,3));
            f4 rE = mk4(E.x, O.y, E.z, O.w);
            f4 rO = mk4(O.x, E.y, O.z, E.w);
            if (r == 0 || r == 4)      { t0 += rE;          t2 += rO; }
            else if (r == 2)           { t0 += sp(3.f)*rE;  t2 += sp(3.f)*rO; }
            else                       { t1 += sp(2.f)*rE;  t3 += sp(2.f)*rO; }
        }
        f4 cEE = py ? t1 : t0, cOE = py ? t0 : t1, cEO = py ? t3 : t2, cOO = py ? t2 : t3;
        const f4 inv_r  = py ? mk4(0.04f,0.05f,0.04f,0.05f)     : mk4(0.05f,0.0625f,0.05f,0.0625f);
        const f4 inv_b  = py ? mk4(0.0625f,0.05f,0.0625f,0.05f) : mk4(0.05f,0.04f,0.05f,0.04f);
        const f4 inv_gr = py ? mk4(0.05f,0.04f,0.05f,0.04f)     : mk4(0.0625f,0.05f,0.0625f,0.05f);
        const f4 inv_gb = py ? mk4(0.05f,0.0625f,0.05f,0.0625f) : mk4(0.04f,0.05f,0.04f,0.05f);
        const f4 inv_g  = py ? mk4(1.f/40.f,1.f/41.f,1.f/40.f,1.f/41.f)
                             : mk4(1.f/41.f,1.f/40.f,1.f/41.f,1.f/40.f);
        f4 rfv = cOE*inv_r, bfv = cEO*inv_b, grfv = cOO*inv_gr, gbfv = cEE*inv_gb;
        f4 gfv = (cEE + cOO)*inv_g;
        ST(34, rfv - gfv); ST(35, bfv - gfv); ST(36, grfv - gbfv);
    }

    f4 ctr = AV(2,2);

    // 1x5 / 5x1 line variances
    {
        f4 sh = AV(2,0)+AV(2,1)+ctr+AV(2,3)+AV(2,4);
        f4 qh = AV(2,0)*AV(2,0)+AV(2,1)*AV(2,1)+ctr*ctr+AV(2,3)*AV(2,3)+AV(2,4)*AV(2,4);
        f4 sv_ = AV(0,2)+AV(1,2)+ctr+AV(3,2)+AV(4,2);
        f4 qv_ = AV(0,2)*AV(0,2)+AV(1,2)*AV(1,2)+ctr*ctr+AV(3,2)*AV(3,2)+AV(4,2)*AV(4,2);
        f4 mh = sh * sp(0.2f), mv = sv_ * sp(0.2f);
        f4 lvh = max4(qh*sp(0.2f) - mh*mh, zero4);
        f4 lvv = max4(qv_*sp(0.2f) - mv*mv, zero4);
        ST(30, lvh); ST(31, lvv);
        f4 lvd = lvh - lvv;
        ST(32, lvd);
        ST(33, abs4(lvd) * rcp4(lvh + lvv + sp(EPS_)));
    }

    ST(19, sp(-0.5f)*(AV(2,0) + AV(2,4)) + ctr);
    ST(20, sp(-0.5f)*(AV(0,2) + AV(4,2)) + ctr);

    // MHC (needs +-2 cross); hgh/hgv centers read from sE
    f4 hghv = CTR(2), hgvv = CTR(3);
    {
        f4 mhcf = sp(0.125f)*( -AV(0,2) + sp(2.f)*AV(1,2) - AV(2,0) + sp(2.f)*AV(2,1) + sp(4.f)*ctr
                               + sp(2.f)*AV(2,3) - AV(2,4) + sp(2.f)*AV(3,2) - AV(4,2) );
        f4 mhc = py ? mk4(mhcf.x, ctr.y, mhcf.z, ctr.w) : mk4(ctr.x, mhcf.y, ctr.z, mhcf.w);
        ST(37, mhc);
        ST(38, mhc - sp(0.5f)*(hghv + hgvv));
        f4 dif = ctr - mhc;
        ST(39, dif * (py ? ev10 : zero4));
        ST(40, dif * (py ? zero4 : ev01));
    }
    ST(21, hghv); ST(22, hgvv);
    ST(23, abs4(hghv - hgvv));
    ST(24, ctr - hghv); ST(25, ctr - hgvv);

    // 3x3 stencils
    {
        f4 lap = AV(1,2) + AV(2,1) - sp(4.f)*ctr + AV(2,3) + AV(3,2);
        f4 hxx = AV(2,1) - sp(2.f)*ctr + AV(2,3);
        f4 hyy = AV(1,2) - sp(2.f)*ctr + AV(3,2);
        f4 hxy = sp(0.25f)*(AV(1,1) - AV(1,3) - AV(3,1) + AV(3,3));
        ST(7, lap); ST(8, hxx); ST(9, hyy); ST(10, hxy);
        ST(29, abs4(hxx) - abs4(hyy));
    }
    ST(14, sp(0.125f)*(sp(-2.f)*AV(1,1) - AV(1,2) - AV(2,1) + AV(2,3) + AV(3,2) + sp(2.f)*AV(3,3)));
    ST(15, sp(0.125f)*(AV(1,2) + sp(2.f)*AV(1,3) - AV(2,1) + AV(2,3) - sp(2.f)*AV(3,1) - AV(3,2)));

    {   // morphological gradient + local mean/var (3x3)
        f4 mx = AV(1,1), mn = mx, s3 = zero4, q3 = zero4;
#pragma unroll
        for (int r = 1; r <= 3; ++r)
#pragma unroll
            for (int i = 1; i <= 3; ++i) {
                f4 v = AV(r,i);
                mx = max4(mx, v);
                mn = mk4(fminf(mn.x,v.x),fminf(mn.y,v.y),fminf(mn.z,v.z),fminf(mn.w,v.w));
                s3 += v; q3 += v*v;
            }
        ST(11, mx - mn);
        f4 lmean = s3 * sp(inv9);
        ST(49, lmean);
        ST(50, max4(q3*sp(inv9) - lmean*lmean, zero4));
    }

    // center-field channels
    {
        f4 gxv = CTR(0), gyv = CTR(1);
        ST(12, gxv); ST(13, gyv);
        ST(16, sqrt4(gxv*gxv + gyv*gyv + sp(EPS_)));
        ST(28, abs4(gxv) - abs4(gyv));
    }
    ST(41, CTR(5)); ST(42, CTR(6)); ST(43, CTR(4));

    // ================= PHASE B: 3x3 box filters over ext fields =================
    {
        f4 jxx = zero4, jyy = zero4, jxy = zero4, reh = zero4, rev = zero4, cke = zero4, ste = zero4;
#pragma unroll
        for (int dy = -1; dy <= 1; ++dy) {
            float g_[6], h_[6], hh_[6], hv_[6], ck_[6], sx_[6], sy_[6];
#pragma unroll
            for (int j = 0; j < 6; ++j) {
                g_[j]  = sE[0][ey+dy][exb-1+j];
                h_[j]  = sE[1][ey+dy][exb-1+j];
                hh_[j] = sE[2][ey+dy][exb-1+j];
                hv_[j] = sE[3][ey+dy][exb-1+j];
                ck_[j] = sE[4][ey+dy][exb-1+j];
                sx_[j] = sE[5][ey+dy][exb-1+j];
                sy_[j] = sE[6][ey+dy][exb-1+j];
            }
            f4 bm_ = AV(dy+2, 1), b0_ = AV(dy+2, 2), bp_ = AV(dy+2, 3);
#pragma unroll
            for (int o = 0; o < 3; ++o) {
                f4 q = SL(g_, o), w = SL(h_, o);
                jxx += q*q; jyy += w*w; jxy += q*w;
                f4 bb = (o == 0) ? bm_ : (o == 1 ? b0_ : bp_);
                f4 rh = bb - SL(hh_, o); reh += rh*rh;
                f4 rv = bb - SL(hv_, o); rev += rv*rv;
                f4 cc = SL(ck_, o); cke += cc*cc;
                f4 s1 = SL(sx_, o), s2 = SL(sy_, o);
                ste += s1*s1 + s2*s2;
            }
        }
        jxx = jxx * sp(inv9); jyy = jyy * sp(inv9); jxy = jxy * sp(inv9);
        f4 trc = jxx + jyy;
        f4 dj  = jxx - jyy;
        f4 lam = sqrt4(dj*dj + sp(4.f)*jxy*jxy + sp(EPS_));
        f4 itr = rcp4(trc + sp(EPS_));
        ST(17, lam * itr);
        ST(18, dj * itr);
        ST(51, trc);
        ST(26, reh * sp(inv9)); ST(27, rev * sp(inv9));
        ST(47, cke * sp(inv9)); ST(48, ste * sp(inv9));
    }

    // ================= masks last =================
    ST(0, py ? ev10 : zero4);
    ST(1, py ? ev01 : ev10);
    ST(2, py ? zero4 : ev01);
    ST(3, py ? ev01 : zero4);
    ST(4, py ? zero4 : ev10);
    ST(5, sp((float)py));
    ST(6, ev01);

#undef ST
#undef AV
#undef SL
#undef CTR
}

extern "C" void kernel_launch(void* const* d_in, const int* in_sizes, int n_in,
                              void* d_out, int out_size, void* d_ws, size_t ws_size,
                              hipStream_t stream) {
    (void)n_in; (void)d_ws; (void)ws_size; (void)out_size;
    const float* bayer = (const float*)d_in[0];
    float* out = (float*)d_out;
    const int B = in_sizes[0] / (H_ * W_);
    dim3 grid(W_ / TX, H_ / TY, B);
    bayer_feat<<<grid, NTHREADS, 0, stream>>>(bayer, out);
}